// Round 12
// baseline (579.927 us; speedup 1.0000x reference)
//
#include <hip/hip_runtime.h>
#include <hip/hip_bf16.h>
#include <cstdint>

#define NNODES 100000
#define NEDGES 1000000
#define HDIM 64
#define ODIM 16
#define NB 8
#define KDIM (HDIM * NB)   // 512 = GEMM inner dim, k = i*8 + b

typedef short short8 __attribute__((ext_vector_type(8)));
typedef float f32x4  __attribute__((ext_vector_type(4)));
union FragU { uint4 u; short8 s; };

__device__ __forceinline__ float asf(uint32_t u) { float f; __builtin_memcpy(&f, &u, 4); return f; }
__device__ __forceinline__ uint32_t asu(float f) { uint32_t u; __builtin_memcpy(&u, &f, 4); return u; }
__device__ __forceinline__ uint16_t f2bf(float f) {
    uint32_t x = asu(f);
    return (uint16_t)((x + 0x7FFFu + ((x >> 16) & 1u)) >> 16);
}
__device__ __forceinline__ uint32_t pack2(float lo, float hi) {
    return (uint32_t)f2bf(lo) | ((uint32_t)f2bf(hi) << 16);
}
__device__ __forceinline__ void fmaC(const float4& cA, const float4& cB, float xs,
                                     float* __restrict__ acc) {
    acc[0] = fmaf(cA.x, xs, acc[0]); acc[1] = fmaf(cA.y, xs, acc[1]);
    acc[2] = fmaf(cA.z, xs, acc[2]); acc[3] = fmaf(cA.w, xs, acc[3]);
    acc[4] = fmaf(cB.x, xs, acc[4]); acc[5] = fmaf(cB.y, xs, acc[5]);
    acc[6] = fmaf(cB.z, xs, acc[6]); acc[7] = fmaf(cB.w, xs, acc[7]);
}

// ---------------------------------------------------------------------------
// cast: f32 feats -> bf16 x  (4 elems/thread)
// ---------------------------------------------------------------------------
__global__ void cast_kernel(const float* __restrict__ in, uint16_t* __restrict__ out, int n4) {
    const int stride = (int)(gridDim.x * blockDim.x);
    for (int idx = (int)(blockIdx.x * blockDim.x + threadIdx.x); idx < n4; idx += stride) {
        float4 v = reinterpret_cast<const float4*>(in)[idx];
        uint2 p;
        p.x = pack2(v.x, v.y);
        p.y = pack2(v.z, v.w);
        reinterpret_cast<uint2*>(out)[idx] = p;
    }
}

// ---------------------------------------------------------------------------
// precompute swizzled bf16 B-fragment table (layer-constant):
// Wg[((kb*OT+ot)*64+lane)*8+j] = bf16(bases[b][i][o]),
//   k=kb*32+(lane>>4)*8+j, o=ot*16+(lane&15), i=k>>3, b=k&7
// ---------------------------------------------------------------------------
template <int DOUT>
__global__ void prep_bfrag_kernel(const float* __restrict__ bases,
                                  uint16_t* __restrict__ Wg) {
    constexpr int OT = DOUT / 16;
    const int total = 16 * OT * 64 * 8;
    for (int idx = (int)(blockIdx.x * blockDim.x + threadIdx.x); idx < total;
         idx += (int)(gridDim.x * blockDim.x)) {
        int j    = idx & 7;
        int ln   = (idx >> 3) & 63;
        int rest = idx >> 9;            // kb*OT + ot
        int ot   = rest & (OT - 1);
        int kb   = rest / OT;
        int k    = kb * 32 + (ln >> 4) * 8 + j;
        int o    = ot * 16 + (ln & 15);
        int i    = k >> 3, b = k & 7;
        Wg[idx] = f2bf(bases[(size_t)(b * HDIM + i) * DOUT + o]);
    }
}

// ---------------------------------------------------------------------------
// CSR build: histogram by dst -> exclusive scan -> scatter packed edge recs
// rec[e] = { src | (etype<<20), norm }  (8 B)
// ---------------------------------------------------------------------------
__global__ void zero_kernel(int* __restrict__ p, int n) {
    for (int i = (int)(blockIdx.x * blockDim.x + threadIdx.x); i < n;
         i += (int)(gridDim.x * blockDim.x)) p[i] = 0;
}

__global__ void hist_kernel(const int* __restrict__ dst, int* __restrict__ cnt, int nE) {
    for (int e = (int)(blockIdx.x * blockDim.x + threadIdx.x); e < nE;
         e += (int)(gridDim.x * blockDim.x)) atomicAdd(&cnt[dst[e]], 1);
}

#define SCAN_B 512
__launch_bounds__(SCAN_B)
__global__ void scan_partial_kernel(const int* __restrict__ cnt, int* __restrict__ bsum, int n) {
    __shared__ int sh[SCAN_B];
    int id = (int)(blockIdx.x * SCAN_B + threadIdx.x);
    sh[threadIdx.x] = (id < n) ? cnt[id] : 0;
    __syncthreads();
    for (int off = SCAN_B / 2; off > 0; off >>= 1) {
        if ((int)threadIdx.x < off) sh[threadIdx.x] += sh[threadIdx.x + off];
        __syncthreads();
    }
    if (threadIdx.x == 0) bsum[blockIdx.x] = sh[0];
}

__launch_bounds__(256)
__global__ void scan_base_kernel(const int* __restrict__ bsum, int* __restrict__ bbase,
                                 int* __restrict__ offs, int nblk, int nNodes) {
    __shared__ int sh[256];
    const int t = (int)threadIdx.x;
    int v = (t < nblk) ? bsum[t] : 0;
    sh[t] = v;
    __syncthreads();
    for (int off = 1; off < 256; off <<= 1) {
        int tmp = (t >= off) ? sh[t - off] : 0;
        __syncthreads();
        sh[t] += tmp;
        __syncthreads();
    }
    if (t < nblk) bbase[t] = sh[t] - v;       // exclusive base per block
    if (t == 255) offs[nNodes] = sh[255];     // grand total
}

__launch_bounds__(SCAN_B)
__global__ void scan_final_kernel(int* __restrict__ cnt, const int* __restrict__ bbase,
                                  int* __restrict__ offs, int n) {
    __shared__ int sh[SCAN_B];
    int id = (int)(blockIdx.x * SCAN_B + threadIdx.x);
    int v = (id < n) ? cnt[id] : 0;
    sh[threadIdx.x] = v;
    __syncthreads();
    for (int off = 1; off < SCAN_B; off <<= 1) {
        int tmp = ((int)threadIdx.x >= off) ? sh[threadIdx.x - off] : 0;
        __syncthreads();
        sh[threadIdx.x] += tmp;
        __syncthreads();
    }
    if (id < n) {
        int excl = sh[threadIdx.x] - v + bbase[blockIdx.x];
        offs[id] = excl;
        cnt[id]  = excl;   // becomes the scatter cursor
    }
}

__global__ void scatter_kernel(const int* __restrict__ src, const int* __restrict__ dst,
                               const int* __restrict__ et, const float* __restrict__ norm,
                               int* __restrict__ cursor, uint2* __restrict__ rec, int nE) {
    for (int e = (int)(blockIdx.x * blockDim.x + threadIdx.x); e < nE;
         e += (int)(gridDim.x * blockDim.x)) {
        int p = atomicAdd(&cursor[dst[e]], 1);
        rec[p] = make_uint2((uint32_t)src[e] | ((uint32_t)et[e] << 20), asu(norm[e]));
    }
}

// ---------------------------------------------------------------------------
// Input-space aggregation: G[d][i][b] = sum_{e in in(d)} norm_e*coeff[r_e,b]*x[src_e,i]
// QUARTER-WAVE per dst node: lane ql in [0,16) covers i = 4*ql .. 4*ql+3 via
// one 8 B x-load. 4 nodes/wave x unroll-4 = 16 independent gather chains.
// Persistent grid-stride, no barriers. FMA order per (d,i,b) identical to
// prior rounds -> bit-identical output.
// ---------------------------------------------------------------------------
__launch_bounds__(256)
__global__ void csr_agg_kernel(const uint16_t* __restrict__ x,
                               const float* __restrict__ coeff,
                               const int* __restrict__ offs,
                               const uint2* __restrict__ rec,
                               uint16_t* __restrict__ G, int nNodes) {
    const int ql  = (int)threadIdx.x & 15;   // lane within quarter-wave
    const int qid = (int)((blockIdx.x * blockDim.x + threadIdx.x) >> 4);
    const int nq  = (int)((gridDim.x * blockDim.x) >> 4);
    for (int d = qid; d < nNodes; d += nq) {
        const int j0 = offs[d], j1 = offs[d + 1];
        float acc[4][NB] = {};               // acc[ii][b], i = 4*ql + ii
        int j = j0;
        for (; j + 4 <= j1; j += 4) {
            const uint2 r0 = rec[j];
            const uint2 r1 = rec[j + 1];
            const uint2 r2 = rec[j + 2];
            const uint2 r3 = rec[j + 3];
            const uint2 g0 = *reinterpret_cast<const uint2*>(
                x + (size_t)(r0.x & 0xFFFFFu) * HDIM + 4 * ql);
            const uint2 g1 = *reinterpret_cast<const uint2*>(
                x + (size_t)(r1.x & 0xFFFFFu) * HDIM + 4 * ql);
            const uint2 g2 = *reinterpret_cast<const uint2*>(
                x + (size_t)(r2.x & 0xFFFFFu) * HDIM + 4 * ql);
            const uint2 g3 = *reinterpret_cast<const uint2*>(
                x + (size_t)(r3.x & 0xFFFFFu) * HDIM + 4 * ql);
            {
                const float4 cA = *reinterpret_cast<const float4*>(coeff + (r0.x >> 20) * NB);
                const float4 cB = *reinterpret_cast<const float4*>(coeff + (r0.x >> 20) * NB + 4);
                const float nm = asf(r0.y);
                fmaC(cA, cB, asf(g0.x << 16) * nm, acc[0]);
                fmaC(cA, cB, asf(g0.x & 0xFFFF0000u) * nm, acc[1]);
                fmaC(cA, cB, asf(g0.y << 16) * nm, acc[2]);
                fmaC(cA, cB, asf(g0.y & 0xFFFF0000u) * nm, acc[3]);
            }
            {
                const float4 cA = *reinterpret_cast<const float4*>(coeff + (r1.x >> 20) * NB);
                const float4 cB = *reinterpret_cast<const float4*>(coeff + (r1.x >> 20) * NB + 4);
                const float nm = asf(r1.y);
                fmaC(cA, cB, asf(g1.x << 16) * nm, acc[0]);
                fmaC(cA, cB, asf(g1.x & 0xFFFF0000u) * nm, acc[1]);
                fmaC(cA, cB, asf(g1.y << 16) * nm, acc[2]);
                fmaC(cA, cB, asf(g1.y & 0xFFFF0000u) * nm, acc[3]);
            }
            {
                const float4 cA = *reinterpret_cast<const float4*>(coeff + (r2.x >> 20) * NB);
                const float4 cB = *reinterpret_cast<const float4*>(coeff + (r2.x >> 20) * NB + 4);
                const float nm = asf(r2.y);
                fmaC(cA, cB, asf(g2.x << 16) * nm, acc[0]);
                fmaC(cA, cB, asf(g2.x & 0xFFFF0000u) * nm, acc[1]);
                fmaC(cA, cB, asf(g2.y << 16) * nm, acc[2]);
                fmaC(cA, cB, asf(g2.y & 0xFFFF0000u) * nm, acc[3]);
            }
            {
                const float4 cA = *reinterpret_cast<const float4*>(coeff + (r3.x >> 20) * NB);
                const float4 cB = *reinterpret_cast<const float4*>(coeff + (r3.x >> 20) * NB + 4);
                const float nm = asf(r3.y);
                fmaC(cA, cB, asf(g3.x << 16) * nm, acc[0]);
                fmaC(cA, cB, asf(g3.x & 0xFFFF0000u) * nm, acc[1]);
                fmaC(cA, cB, asf(g3.y << 16) * nm, acc[2]);
                fmaC(cA, cB, asf(g3.y & 0xFFFF0000u) * nm, acc[3]);
            }
        }
        for (; j < j1; j++) {
            const uint2 r0 = rec[j];
            const uint2 g0 = *reinterpret_cast<const uint2*>(
                x + (size_t)(r0.x & 0xFFFFFu) * HDIM + 4 * ql);
            const float4 cA = *reinterpret_cast<const float4*>(coeff + (r0.x >> 20) * NB);
            const float4 cB = *reinterpret_cast<const float4*>(coeff + (r0.x >> 20) * NB + 4);
            const float nm = asf(r0.y);
            fmaC(cA, cB, asf(g0.x << 16) * nm, acc[0]);
            fmaC(cA, cB, asf(g0.x & 0xFFFF0000u) * nm, acc[1]);
            fmaC(cA, cB, asf(g0.y << 16) * nm, acc[2]);
            fmaC(cA, cB, asf(g0.y & 0xFFFF0000u) * nm, acc[3]);
        }
        // lane ql owns k = 32*ql .. 32*ql+31  (ii-major, b-minor: k = (4ql+ii)*8+b)
        uint16_t* gp = G + (size_t)d * KDIM + 32 * ql;
#pragma unroll
        for (int ii = 0; ii < 4; ii++) {
            uint4 pv;
            pv.x = pack2(acc[ii][0], acc[ii][1]);
            pv.y = pack2(acc[ii][2], acc[ii][3]);
            pv.z = pack2(acc[ii][4], acc[ii][5]);
            pv.w = pack2(acc[ii][6], acc[ii][7]);
            *reinterpret_cast<uint4*>(gp + 8 * ii) = pv;
        }
    }
}

// ---------------------------------------------------------------------------
// MFMA GEMM, register-B: [N,512] bf16 (G) x [512,64] via precomputed Wg.
// Block 256 = 4 waves; wave w -> o-tile w; 16-node tile shared via L1.
// mfma_f32_16x16x32_bf16: A[m=lane&15][k=(lane>>4)*8+j], B[k][n=lane&15],
// C col=lane&15, row=(lane>>4)*4+reg.
// ---------------------------------------------------------------------------
__launch_bounds__(256)
__global__ void proj_hidden_kernel(const uint16_t* __restrict__ G,
                                   const uint16_t* __restrict__ Wg,
                                   const float* __restrict__ bias,
                                   uint16_t* __restrict__ xout, int nNodes) {
    constexpr int OT = 4;
    const int t    = (int)threadIdx.x;
    const int lane = t & 63;
    const int ot   = t >> 6;            // wave = o-tile
    const int q    = lane >> 4;
    const int c    = lane & 15;

    FragU bfr[16];
#pragma unroll
    for (int kb = 0; kb < 16; kb++)
        bfr[kb].u = *reinterpret_cast<const uint4*>(Wg + (size_t)((kb * OT + ot) * 64 + lane) * 8);
    const float bv = bias[ot * 16 + c];

    const int nTiles = (nNodes + 15) / 16;
    for (int tile = blockIdx.x; tile < nTiles; tile += gridDim.x) {
        const int n0 = tile * 16;
        int arow = n0 + c;
        if (arow > nNodes - 1) arow = nNodes - 1;
        const uint16_t* gp = G + (size_t)arow * KDIM + q * 8;

        f32x4 acc = {0.f, 0.f, 0.f, 0.f};
#pragma unroll
        for (int kb = 0; kb < 16; kb++) {
            FragU a;
            a.u = *reinterpret_cast<const uint4*>(gp + kb * 32);
            acc = __builtin_amdgcn_mfma_f32_16x16x32_bf16(a.s, bfr[kb].s, acc, 0, 0, 0);
        }

#pragma unroll
        for (int r = 0; r < 4; r++) {
            const int node = n0 + q * 4 + r;
            if (node < nNodes) {
                float v = fmaxf(acc[r] + bv, 0.f);
                xout[(size_t)node * HDIM + ot * 16 + c] = f2bf(v);
            }
        }
    }
}

// DOUT=16, f32 out, no relu. Block 256 = 4 waves; wave w -> rowgroup w of a
// 64-node tile; single o-tile (OT=1).
__launch_bounds__(256)
__global__ void proj_out_kernel(const uint16_t* __restrict__ G,
                                const uint16_t* __restrict__ Wg,
                                const float* __restrict__ bias,
                                float* __restrict__ out, int nNodes) {
    const int t    = (int)threadIdx.x;
    const int lane = t & 63;
    const int w    = t >> 6;            // rowgroup
    const int q    = lane >> 4;
    const int c    = lane & 15;

    FragU bfr[16];
#pragma unroll
    for (int kb = 0; kb < 16; kb++)
        bfr[kb].u = *reinterpret_cast<const uint4*>(Wg + (size_t)(kb * 64 + lane) * 8);
    const float bv = bias[c];

    const int nTiles = (nNodes + 63) / 64;
    for (int tile = blockIdx.x; tile < nTiles; tile += gridDim.x) {
        const int n0 = tile * 64 + w * 16;
        int arow = n0 + c;
        if (arow > nNodes - 1) arow = nNodes - 1;
        const uint16_t* gp = G + (size_t)arow * KDIM + q * 8;

        f32x4 acc = {0.f, 0.f, 0.f, 0.f};
#pragma unroll
        for (int kb = 0; kb < 16; kb++) {
            FragU a;
            a.u = *reinterpret_cast<const uint4*>(gp + kb * 32);
            acc = __builtin_amdgcn_mfma_f32_16x16x32_bf16(a.s, bfr[kb].s, acc, 0, 0, 0);
        }

#pragma unroll
        for (int r = 0; r < 4; r++) {
            const int node = n0 + q * 4 + r;
            if (node < nNodes) out[(size_t)node * ODIM + c] = acc[r] + bv;
        }
    }
}

extern "C" void kernel_launch(void* const* d_in, const int* in_sizes, int n_in,
                              void* d_out, int out_size, void* d_ws, size_t ws_size,
                              hipStream_t stream) {
    const float* feats  = (const float*)d_in[0];
    const float* coeff0 = (const float*)d_in[1];
    const float* bases0 = (const float*)d_in[2];
    const float* bias0  = (const float*)d_in[3];
    const float* coeff1 = (const float*)d_in[4];
    const float* bases1 = (const float*)d_in[5];
    const float* bias1  = (const float*)d_in[6];
    const float* coeff2 = (const float*)d_in[7];
    const float* bases2 = (const float*)d_in[8];
    const float* bias2  = (const float*)d_in[9];
    const int*   src    = (const int*)d_in[10];
    const int*   dst    = (const int*)d_in[11];
    const int*   etype  = (const int*)d_in[12];
    const float* norm   = (const float*)d_in[13];
    float* out = (float*)d_out;

    char* base = (char*)d_ws;
    // layout: G 102.4MB | x0 12.8MB | x1 12.8MB | offs | curs | bsum | bbase
    //         | Wg0 64KB | Wg1 64KB | Wg2 16KB | rec 8MB   (~137 MB total)
    uint16_t* G  = (uint16_t*)base;
    uint16_t* x0 = (uint16_t*)(base + 102400000);
    uint16_t* x1 = (uint16_t*)(base + 115200000);
    const size_t OFF_OFFS  = 128000000;
    const size_t OFF_CURS  = OFF_OFFS  + 400016;
    const size_t OFF_BSUM  = OFF_CURS  + 400016;
    const size_t OFF_BBASE = OFF_BSUM  + 1024;
    const size_t OFF_WG0   = OFF_BBASE + 1024;     // 128,802,080 (16B aligned)
    const size_t OFF_WG1   = OFF_WG0   + 65536;
    const size_t OFF_WG2   = OFF_WG1   + 65536;
    const size_t OFF_REC   = OFF_WG2   + 16384;    // 128,949,536 (8B aligned)
    int*      offs  = (int*)(base + OFF_OFFS);
    int*      curs  = (int*)(base + OFF_CURS);
    int*      bsum  = (int*)(base + OFF_BSUM);
    int*      bbase = (int*)(base + OFF_BBASE);
    uint16_t* Wg0   = (uint16_t*)(base + OFF_WG0);
    uint16_t* Wg1   = (uint16_t*)(base + OFF_WG1);
    uint16_t* Wg2   = (uint16_t*)(base + OFF_WG2);
    uint2*    rec   = (uint2*)(base + OFF_REC);

    const int nblk = (NNODES + SCAN_B - 1) / SCAN_B;   // 196 <= 256

    // ---- precompute swizzled B-fragment tables (layer-constant)
    hipLaunchKernelGGL((prep_bfrag_kernel<64>), dim3(32), dim3(256), 0, stream, bases0, Wg0);
    hipLaunchKernelGGL((prep_bfrag_kernel<64>), dim3(32), dim3(256), 0, stream, bases1, Wg1);
    hipLaunchKernelGGL((prep_bfrag_kernel<16>), dim3(8), dim3(256), 0, stream, bases2, Wg2);

    // ---- CSR build (graph identical across layers; built once per call)
    hipLaunchKernelGGL(zero_kernel, dim3(256), dim3(256), 0, stream, curs, NNODES);
    hipLaunchKernelGGL(hist_kernel, dim3(2048), dim3(256), 0, stream, dst, curs, NEDGES);
    hipLaunchKernelGGL(scan_partial_kernel, dim3(nblk), dim3(SCAN_B), 0, stream, curs, bsum, NNODES);
    hipLaunchKernelGGL(scan_base_kernel, dim3(1), dim3(256), 0, stream, bsum, bbase, offs, nblk, NNODES);
    hipLaunchKernelGGL(scan_final_kernel, dim3(nblk), dim3(SCAN_B), 0, stream, curs, bbase, offs, NNODES);
    hipLaunchKernelGGL(scatter_kernel, dim3(2048), dim3(256), 0, stream,
                       src, dst, etype, norm, curs, rec, NEDGES);

    // ---- x0 = bf16(feats)
    hipLaunchKernelGGL(cast_kernel, dim3(2048), dim3(256), 0, stream,
                       feats, x0, NNODES * HDIM / 4);

    // ---- Layer 0
    hipLaunchKernelGGL(csr_agg_kernel, dim3(2048), dim3(256), 0, stream,
                       x0, coeff0, offs, rec, G, NNODES);
    hipLaunchKernelGGL(proj_hidden_kernel, dim3(2048), dim3(256), 0, stream,
                       G, Wg0, bias0, x1, NNODES);
    // ---- Layer 1
    hipLaunchKernelGGL(csr_agg_kernel, dim3(2048), dim3(256), 0, stream,
                       x1, coeff1, offs, rec, G, NNODES);
    hipLaunchKernelGGL(proj_hidden_kernel, dim3(2048), dim3(256), 0, stream,
                       G, Wg1, bias1, x0, NNODES);
    // ---- Layer 2
    hipLaunchKernelGGL(csr_agg_kernel, dim3(2048), dim3(256), 0, stream,
                       x0, coeff2, offs, rec, G, NNODES);
    hipLaunchKernelGGL(proj_out_kernel, dim3(1024), dim3(256), 0, stream,
                       G, Wg2, bias2, out, NNODES);
}